// Round 1
// baseline (94.658 us; speedup 1.0000x reference)
//
#include <hip/hip_runtime.h>
#include <math.h>

#define REG_COEF 25.0f
#define B 8
#define H 3
#define N 4096

static constexpr int NX = B * N;          // 32768 packed sample points
static constexpr int NY = B * H * N;      // 98304 packed reflected points
static constexpr int NM = 2 * B * H * N;  // 196608 per-query mins

// ws layout (float units):
//   [0, 131072)           : X packed float4 (x,y,z,|x|^2)   (32768 float4)
//   [131072, 524288)      : Y packed float4 (reflected + |y|^2) (98304 float4)
//   [524288, 720896)      : mins (196608 floats)
//   [720896]              : acc
//   [720897]              : regterm (25 * reg)

__global__ void prep_kernel(const float* __restrict__ pts, const float* __restrict__ ypred,
                            float4* __restrict__ X, float4* __restrict__ Y,
                            float* __restrict__ mins, float* __restrict__ acc,
                            float* __restrict__ regterm)
{
    int idx = blockIdx.x * blockDim.x + threadIdx.x;
    if (idx == 0) {
        acc[0] = 0.f;
        float reg = 0.f;
        for (int b = 0; b < B; ++b) {
            float n[H][3];
            #pragma unroll
            for (int h = 0; h < H; ++h) {
                float a0 = ypred[b * 12 + h * 4 + 0];
                float a1 = ypred[b * 12 + h * 4 + 1];
                float a2 = ypred[b * 12 + h * 4 + 2];
                float inv = rsqrtf(a0 * a0 + a1 * a1 + a2 * a2);
                n[h][0] = a0 * inv; n[h][1] = a1 * inv; n[h][2] = a2 * inv;
            }
            float s = 0.f;
            #pragma unroll
            for (int c = 0; c < H; ++c)
                #pragma unroll
                for (int e = 0; e < H; ++e) {
                    float g = n[c][0] * n[e][0] + n[c][1] * n[e][1] + n[c][2] * n[e][2];
                    if (c == e) g -= 1.f;
                    s += g * g;
                }
            reg += sqrtf(s);
        }
        regterm[0] = REG_COEF * reg;
    }

    if (idx < NX) {
        // pack sample points with squared norm
        float x0 = pts[(size_t)idx * 3 + 0];
        float x1 = pts[(size_t)idx * 3 + 1];
        float x2 = pts[(size_t)idx * 3 + 2];
        X[idx] = make_float4(x0, x1, x2, x0 * x0 + x1 * x1 + x2 * x2);
    } else if (idx < NX + NY) {
        int t = idx - NX;            // (b*H + h)*N + nn
        int nn = t & (N - 1);
        int bh = t >> 12;
        int b = bh / H, h = bh - b * H;
        float a0 = ypred[b * 12 + h * 4 + 0];
        float a1 = ypred[b * 12 + h * 4 + 1];
        float a2 = ypred[b * 12 + h * 4 + 2];
        float off = ypred[b * 12 + h * 4 + 3];
        float inv = rsqrtf(a0 * a0 + a1 * a1 + a2 * a2);
        a0 *= inv; a1 *= inv; a2 *= inv;
        const float* p = pts + ((size_t)b * N + nn) * 3;
        float x0 = p[0], x1 = p[1], x2 = p[2];
        float dist = a0 * x0 + a1 * x1 + a2 * x2 + off;
        float y0 = fmaf(-2.f * dist, a0, x0);
        float y1 = fmaf(-2.f * dist, a1, x1);
        float y2 = fmaf(-2.f * dist, a2, x2);
        Y[t] = make_float4(y0, y1, y2, y0 * y0 + y1 * y1 + y2 * y2);
    } else if (idx < NX + NY + NM) {
        mins[idx - NX - NY] = __uint_as_float(0x7F800000u);  // +inf
    }
}

// 768 blocks: [tslice(4)][qchunk(4)][h(3)][b(8)][dir(2)]
// each block: 256 threads x Q=4 queries, scans 1024 targets staged in LDS.
__global__ __launch_bounds__(256) void chamfer_kernel(const float4* __restrict__ X,
                                                      const float4* __restrict__ Y,
                                                      float* __restrict__ mins)
{
    __shared__ float4 tile[1024];
    int bid = blockIdx.x;
    int tslice = bid & 3;
    int qchunk = (bid >> 2) & 3;
    int hh = (bid >> 4) % 3;
    int tmp = (bid >> 4) / 3;   // 0..15
    int b = tmp & 7;
    int dir = tmp >> 3;

    const float4* Xb = X + b * N;
    const float4* Yb = Y + (b * H + hh) * N;
    const float4* q;
    const float4* t;
    float* mb;
    if (dir == 0) { q = Xb; t = Yb; mb = mins + (b * H + hh) * N; }
    else          { q = Yb; t = Xb; mb = mins + B * H * N + (b * H + hh) * N; }
    q += qchunk * 1024;
    mb += qchunk * 1024;
    t += tslice * 1024;

    int tid = threadIdx.x;
    for (int i = tid; i < 1024; i += 256) tile[i] = t[i];
    __syncthreads();

    float4 P[4];
    float m[4];
    #pragma unroll
    for (int k = 0; k < 4; ++k) { P[k] = q[tid + 256 * k]; m[k] = INFINITY; }

    #pragma unroll 8
    for (int j = 0; j < 1024; ++j) {
        float4 T = tile[j];
        #pragma unroll
        for (int k = 0; k < 4; ++k) {
            float dot = fmaf(P[k].x, T.x, fmaf(P[k].y, T.y, P[k].z * T.z));
            float v = fmaf(-2.f, dot, T.w);   // |t|^2 - 2 q.t
            m[k] = fminf(m[k], v);
        }
    }

    #pragma unroll
    for (int k = 0; k < 4; ++k) {
        float v = fmaxf(m[k] + P[k].w, 0.f);  // + |q|^2, clamp for uint-min ordering
        atomicMin((unsigned int*)&mb[tid + 256 * k], __float_as_uint(v));
    }
}

__global__ void reduce_kernel(const float* __restrict__ mins, float* __restrict__ acc)
{
    int tid = blockIdx.x * blockDim.x + threadIdx.x;  // 192*256 = 49152 threads
    float s = 0.f;
    #pragma unroll
    for (int k = 0; k < 4; ++k) s += mins[tid + k * 49152];
    #pragma unroll
    for (int off = 32; off > 0; off >>= 1) s += __shfl_down(s, off);
    if ((threadIdx.x & 63) == 0) atomicAdd(acc, s);
}

__global__ void finalize_kernel(const float* __restrict__ acc,
                                const float* __restrict__ regterm,
                                float* __restrict__ out)
{
    if (threadIdx.x == 0) out[0] = acc[0] + regterm[0];
}

extern "C" void kernel_launch(void* const* d_in, const int* in_sizes, int n_in,
                              void* d_out, int out_size, void* d_ws, size_t ws_size,
                              hipStream_t stream)
{
    const float* pts = (const float*)d_in[0];   // (8,4096,3) fp32
    const float* yp  = (const float*)d_in[1];   // (8,3,4) fp32
    float* out = (float*)d_out;
    float* ws  = (float*)d_ws;

    float4* X = (float4*)ws;                    // 32768 float4
    float4* Y = (float4*)(ws + 131072);         // 98304 float4
    float* mins = ws + 524288;                  // 196608 floats
    float* acc = ws + 524288 + 196608;
    float* regterm = acc + 1;

    prep_kernel<<<1280, 256, 0, stream>>>(pts, yp, X, Y, mins, acc, regterm);
    chamfer_kernel<<<768, 256, 0, stream>>>(X, Y, mins);
    reduce_kernel<<<192, 256, 0, stream>>>(mins, acc);
    finalize_kernel<<<1, 64, 0, stream>>>(acc, regterm, out);
}

// Round 2
// 84.367 us; speedup vs baseline: 1.1220x; 1.1220x over previous
//
#include <hip/hip_runtime.h>
#include <math.h>

#define REG_COEF 25.0f
#define B 8
#define H 3
#define N 4096

static constexpr int NX = B * N;          // 32768 packed sample points
static constexpr int NY = B * H * N;      // 98304 packed reflected points
static constexpr int NM = 2 * B * H * N;  // 196608 per-query mins

// ws layout (float units):
//   [0, 131072)           : X packed float4 (x,y,z,|x|^2)   (32768 float4)
//   [131072, 524288)      : Y packed float4 (reflected + |y|^2) (98304 float4)
//   [524288, 720896)      : mins (196608 floats)
//   [720896]              : acc
//   [720897]              : regterm (25 * reg)

__global__ void prep_kernel(const float* __restrict__ pts, const float* __restrict__ ypred,
                            float4* __restrict__ X, float4* __restrict__ Y,
                            float* __restrict__ mins, float* __restrict__ acc,
                            float* __restrict__ regterm)
{
    int idx = blockIdx.x * blockDim.x + threadIdx.x;
    if (idx == 0) {
        acc[0] = 0.f;
        float reg = 0.f;
        for (int b = 0; b < B; ++b) {
            float n[H][3];
            #pragma unroll
            for (int h = 0; h < H; ++h) {
                float a0 = ypred[b * 12 + h * 4 + 0];
                float a1 = ypred[b * 12 + h * 4 + 1];
                float a2 = ypred[b * 12 + h * 4 + 2];
                float inv = rsqrtf(a0 * a0 + a1 * a1 + a2 * a2);
                n[h][0] = a0 * inv; n[h][1] = a1 * inv; n[h][2] = a2 * inv;
            }
            float s = 0.f;
            #pragma unroll
            for (int c = 0; c < H; ++c)
                #pragma unroll
                for (int e = 0; e < H; ++e) {
                    float g = n[c][0] * n[e][0] + n[c][1] * n[e][1] + n[c][2] * n[e][2];
                    if (c == e) g -= 1.f;
                    s += g * g;
                }
            reg += sqrtf(s);
        }
        regterm[0] = REG_COEF * reg;
    }

    if (idx < NX) {
        float x0 = pts[(size_t)idx * 3 + 0];
        float x1 = pts[(size_t)idx * 3 + 1];
        float x2 = pts[(size_t)idx * 3 + 2];
        X[idx] = make_float4(x0, x1, x2, x0 * x0 + x1 * x1 + x2 * x2);
    } else if (idx < NX + NY) {
        int t = idx - NX;            // (b*H + h)*N + nn
        int nn = t & (N - 1);
        int bh = t >> 12;
        int b = bh / H, h = bh - b * H;
        float a0 = ypred[b * 12 + h * 4 + 0];
        float a1 = ypred[b * 12 + h * 4 + 1];
        float a2 = ypred[b * 12 + h * 4 + 2];
        float off = ypred[b * 12 + h * 4 + 3];
        float inv = rsqrtf(a0 * a0 + a1 * a1 + a2 * a2);
        a0 *= inv; a1 *= inv; a2 *= inv;
        const float* p = pts + ((size_t)b * N + nn) * 3;
        float x0 = p[0], x1 = p[1], x2 = p[2];
        float dist = a0 * x0 + a1 * x1 + a2 * x2 + off;
        float y0 = fmaf(-2.f * dist, a0, x0);
        float y1 = fmaf(-2.f * dist, a1, x1);
        float y2 = fmaf(-2.f * dist, a2, x2);
        Y[t] = make_float4(y0, y1, y2, y0 * y0 + y1 * y1 + y2 * y2);
    } else if (idx < NX + NY + NM) {
        mins[idx - NX - NY] = __uint_as_float(0x7F800000u);  // +inf
    }
}

// 1536 blocks: [tslice(8)][qchunk(4)][h(3)][b(8)][dir(2)]
// each block: 256 threads x Q=4 queries, scans 512 targets staged in LDS.
__global__ __launch_bounds__(256) void chamfer_kernel(const float4* __restrict__ X,
                                                      const float4* __restrict__ Y,
                                                      float* __restrict__ mins)
{
    __shared__ float4 tile[512];
    int bid = blockIdx.x;
    int tslice = bid & 7;
    int qchunk = (bid >> 3) & 3;
    int hh = (bid >> 5) % 3;
    int tmp = (bid >> 5) / 3;   // 0..15
    int b = tmp & 7;
    int dir = tmp >> 3;

    const float4* Xb = X + b * N;
    const float4* Yb = Y + (b * H + hh) * N;
    const float4* q;
    const float4* t;
    float* mb;
    if (dir == 0) { q = Xb; t = Yb; mb = mins + (b * H + hh) * N; }
    else          { q = Yb; t = Xb; mb = mins + B * H * N + (b * H + hh) * N; }
    q += qchunk * 1024;
    mb += qchunk * 1024;
    t += tslice * 512;

    int tid = threadIdx.x;
    tile[tid] = t[tid];
    tile[tid + 256] = t[tid + 256];
    __syncthreads();

    // query regs: (-2x, -2y, -2z) and |q|^2
    float qx[4], qy[4], qz[4], qw[4], m[4];
    #pragma unroll
    for (int k = 0; k < 4; ++k) {
        float4 P = q[tid + 256 * k];
        qx[k] = -2.f * P.x; qy[k] = -2.f * P.y; qz[k] = -2.f * P.z;
        qw[k] = P.w; m[k] = INFINITY;
    }

    #pragma unroll 4
    for (int j = 0; j < 512; j += 2) {
        float4 Ta = tile[j];
        float4 Tb = tile[j + 1];
        #pragma unroll
        for (int k = 0; k < 4; ++k) {
            float va = fmaf(qx[k], Ta.x, fmaf(qy[k], Ta.y, fmaf(qz[k], Ta.z, Ta.w)));
            float vb = fmaf(qx[k], Tb.x, fmaf(qy[k], Tb.y, fmaf(qz[k], Tb.z, Tb.w)));
            m[k] = fminf(m[k], fminf(va, vb));   // -> v_min3_f32
        }
    }

    #pragma unroll
    for (int k = 0; k < 4; ++k) {
        float v = fmaxf(m[k] + qw[k], 0.f);  // + |q|^2, clamp for uint-min ordering
        atomicMin((unsigned int*)&mb[tid + 256 * k], __float_as_uint(v));
    }
}

__global__ void reduce_kernel(const float* __restrict__ mins, float* __restrict__ acc)
{
    int tid = blockIdx.x * blockDim.x + threadIdx.x;  // 192*256 = 49152 threads
    float s = 0.f;
    #pragma unroll
    for (int k = 0; k < 4; ++k) s += mins[tid + k * 49152];
    #pragma unroll
    for (int off = 32; off > 0; off >>= 1) s += __shfl_down(s, off);
    if ((threadIdx.x & 63) == 0) atomicAdd(acc, s);
}

__global__ void finalize_kernel(const float* __restrict__ acc,
                                const float* __restrict__ regterm,
                                float* __restrict__ out)
{
    if (threadIdx.x == 0) out[0] = acc[0] + regterm[0];
}

extern "C" void kernel_launch(void* const* d_in, const int* in_sizes, int n_in,
                              void* d_out, int out_size, void* d_ws, size_t ws_size,
                              hipStream_t stream)
{
    const float* pts = (const float*)d_in[0];   // (8,4096,3) fp32
    const float* yp  = (const float*)d_in[1];   // (8,3,4) fp32
    float* out = (float*)d_out;
    float* ws  = (float*)d_ws;

    float4* X = (float4*)ws;                    // 32768 float4
    float4* Y = (float4*)(ws + 131072);         // 98304 float4
    float* mins = ws + 524288;                  // 196608 floats
    float* acc = ws + 524288 + 196608;
    float* regterm = acc + 1;

    prep_kernel<<<1280, 256, 0, stream>>>(pts, yp, X, Y, mins, acc, regterm);
    chamfer_kernel<<<1536, 256, 0, stream>>>(X, Y, mins);
    reduce_kernel<<<192, 256, 0, stream>>>(mins, acc);
    finalize_kernel<<<1, 64, 0, stream>>>(acc, regterm, out);
}

// Round 3
// 80.696 us; speedup vs baseline: 1.1730x; 1.0455x over previous
//
#include <hip/hip_runtime.h>
#include <math.h>

#define REG_COEF 25.0f
#define B 8
#define H 3
#define N 4096

static constexpr int NX = B * N;          // 32768 packed sample points
static constexpr int NY = B * H * N;      // 98304 packed reflected points
static constexpr int NM = 2 * B * H * N;  // 196608 per-query mins

// ws layout (float units):
//   [0, 131072)           : X packed float4 (x,y,z,|x|^2)   (32768 float4)
//   [131072, 524288)      : Y packed float4 (reflected + |y|^2) (98304 float4)
//   [524288, 720896)      : mins (196608 floats)

__global__ void prep_kernel(const float* __restrict__ pts, const float* __restrict__ ypred,
                            float4* __restrict__ X, float4* __restrict__ Y,
                            float* __restrict__ mins, float* __restrict__ out)
{
    int idx = blockIdx.x * blockDim.x + threadIdx.x;
    if (idx == 0) {
        float reg = 0.f;
        for (int b = 0; b < B; ++b) {
            float n[H][3];
            #pragma unroll
            for (int h = 0; h < H; ++h) {
                float a0 = ypred[b * 12 + h * 4 + 0];
                float a1 = ypred[b * 12 + h * 4 + 1];
                float a2 = ypred[b * 12 + h * 4 + 2];
                float inv = rsqrtf(a0 * a0 + a1 * a1 + a2 * a2);
                n[h][0] = a0 * inv; n[h][1] = a1 * inv; n[h][2] = a2 * inv;
            }
            float s = 0.f;
            #pragma unroll
            for (int c = 0; c < H; ++c)
                #pragma unroll
                for (int e = 0; e < H; ++e) {
                    float g = n[c][0] * n[e][0] + n[c][1] * n[e][1] + n[c][2] * n[e][2];
                    if (c == e) g -= 1.f;
                    s += g * g;
                }
            reg += sqrtf(s);
        }
        out[0] = REG_COEF * reg;   // reduce_kernel accumulates on top
    }

    if (idx < NX) {
        float x0 = pts[(size_t)idx * 3 + 0];
        float x1 = pts[(size_t)idx * 3 + 1];
        float x2 = pts[(size_t)idx * 3 + 2];
        X[idx] = make_float4(x0, x1, x2, x0 * x0 + x1 * x1 + x2 * x2);
    } else if (idx < NX + NY) {
        int t = idx - NX;            // (b*H + h)*N + nn
        int nn = t & (N - 1);
        int bh = t >> 12;
        int b = bh / H, h = bh - b * H;
        float a0 = ypred[b * 12 + h * 4 + 0];
        float a1 = ypred[b * 12 + h * 4 + 1];
        float a2 = ypred[b * 12 + h * 4 + 2];
        float off = ypred[b * 12 + h * 4 + 3];
        float inv = rsqrtf(a0 * a0 + a1 * a1 + a2 * a2);
        a0 *= inv; a1 *= inv; a2 *= inv;
        const float* p = pts + ((size_t)b * N + nn) * 3;
        float x0 = p[0], x1 = p[1], x2 = p[2];
        float dist = a0 * x0 + a1 * x1 + a2 * x2 + off;
        float y0 = fmaf(-2.f * dist, a0, x0);
        float y1 = fmaf(-2.f * dist, a1, x1);
        float y2 = fmaf(-2.f * dist, a2, x2);
        Y[t] = make_float4(y0, y1, y2, y0 * y0 + y1 * y1 + y2 * y2);
    } else if (idx < NX + NY + NM) {
        mins[idx - NX - NY] = __uint_as_float(0x7F800000u);  // +inf
    }
}

// 1536 blocks: [tslice(16)][qchunk(2)][h(3)][b(8)][dir(2)]
// each block: 256 threads x Q=8 queries, scans 256 targets staged in LDS.
__global__ __launch_bounds__(256) void chamfer_kernel(const float4* __restrict__ X,
                                                      const float4* __restrict__ Y,
                                                      float* __restrict__ mins)
{
    __shared__ float4 tile[256];
    int bid = blockIdx.x;
    int tslice = bid & 15;
    int qchunk = (bid >> 4) & 1;
    int rest = bid >> 5;        // 0..47
    int hh = rest % 3;
    int tmp = rest / 3;         // 0..15
    int b = tmp & 7;
    int dir = tmp >> 3;

    const float4* Xb = X + b * N;
    const float4* Yb = Y + (b * H + hh) * N;
    const float4* q;
    const float4* t;
    float* mb;
    if (dir == 0) { q = Xb; t = Yb; mb = mins + (b * H + hh) * N; }
    else          { q = Yb; t = Xb; mb = mins + B * H * N + (b * H + hh) * N; }
    q += qchunk * 2048;
    mb += qchunk * 2048;
    t += tslice * 256;

    int tid = threadIdx.x;
    tile[tid] = t[tid];
    __syncthreads();

    // query regs: (-2x, -2y, -2z) and |q|^2
    float qx[8], qy[8], qz[8], qw[8], m[8];
    #pragma unroll
    for (int k = 0; k < 8; ++k) {
        float4 P = q[tid + 256 * k];
        qx[k] = -2.f * P.x; qy[k] = -2.f * P.y; qz[k] = -2.f * P.z;
        qw[k] = P.w; m[k] = INFINITY;
    }

    #pragma unroll 4
    for (int j = 0; j < 256; j += 2) {
        float4 Ta = tile[j];
        float4 Tb = tile[j + 1];
        #pragma unroll
        for (int k = 0; k < 8; ++k) {
            float va = fmaf(qx[k], Ta.x, fmaf(qy[k], Ta.y, fmaf(qz[k], Ta.z, Ta.w)));
            float vb = fmaf(qx[k], Tb.x, fmaf(qy[k], Tb.y, fmaf(qz[k], Tb.z, Tb.w)));
            m[k] = fminf(m[k], fminf(va, vb));   // -> v_min3_f32
        }
    }

    #pragma unroll
    for (int k = 0; k < 8; ++k) {
        float v = fmaxf(m[k] + qw[k], 0.f);  // + |q|^2, clamp for uint-min ordering
        atomicMin((unsigned int*)&mb[tid + 256 * k], __float_as_uint(v));
    }
}

__global__ void reduce_kernel(const float* __restrict__ mins, float* __restrict__ out)
{
    int tid = blockIdx.x * blockDim.x + threadIdx.x;  // 192*256 = 49152 threads
    float s = 0.f;
    #pragma unroll
    for (int k = 0; k < 4; ++k) s += mins[tid + k * 49152];
    #pragma unroll
    for (int off = 32; off > 0; off >>= 1) s += __shfl_down(s, off);
    if ((threadIdx.x & 63) == 0) atomicAdd(out, s);
}

extern "C" void kernel_launch(void* const* d_in, const int* in_sizes, int n_in,
                              void* d_out, int out_size, void* d_ws, size_t ws_size,
                              hipStream_t stream)
{
    const float* pts = (const float*)d_in[0];   // (8,4096,3) fp32
    const float* yp  = (const float*)d_in[1];   // (8,3,4) fp32
    float* out = (float*)d_out;
    float* ws  = (float*)d_ws;

    float4* X = (float4*)ws;                    // 32768 float4
    float4* Y = (float4*)(ws + 131072);         // 98304 float4
    float* mins = ws + 524288;                  // 196608 floats

    prep_kernel<<<1280, 256, 0, stream>>>(pts, yp, X, Y, mins, out);
    chamfer_kernel<<<1536, 256, 0, stream>>>(X, Y, mins);
    reduce_kernel<<<192, 256, 0, stream>>>(mins, out);
}